// Round 8
// baseline (3172.825 us; speedup 1.0000x reference)
//
#include <hip/hip_runtime.h>

#define SEQ   1024
#define DIN   64
#define NHID  256
#define NGRP  16
#define NBLK  128
#define NTHR  64

typedef _Float16 f16x8 __attribute__((ext_vector_type(8)));
typedef float    f32x4 __attribute__((ext_vector_type(4)));
typedef unsigned int u32;
typedef u32      u32x4 __attribute__((ext_vector_type(4)));

#define MFMA16(a,b,c) __builtin_amdgcn_mfma_f32_16x16x32_f16((a),(b),(c),0,0,0)

// All exchange ops at the agent coherence point (sc0 sc1) — R4-proven semantics.
#define PLOAD(d, b, O) \
  asm volatile("global_load_dwordx4 %0, %1, off offset:" #O " sc0 sc1" \
               : "=v"(d) : "v"(b) : "memory")
#define PSTORE(b, d) \
  asm volatile("global_store_dwordx4 %0, %1, off sc0 sc1" :: "v"(b), "v"(d) : "memory")
#define SSTORE(b, v) \
  asm volatile("global_store_dword %0, %1, off sc0 sc1" :: "v"(b), "v"(v) : "memory")
#define WAITBIND2(a,b) do{ \
  asm volatile("s_waitcnt vmcnt(0)" : "+v"(a), "+v"(b) :: "memory"); \
  __builtin_amdgcn_sched_barrier(0); }while(0)
#define WAITBIND8(a0,a1,a2,a3,a4,a5,a6,a7) do{ \
  asm volatile("s_waitcnt vmcnt(0)" : "+v"(a0),"+v"(a1),"+v"(a2),"+v"(a3), \
               "+v"(a4),"+v"(a5),"+v"(a6),"+v"(a7) :: "memory"); \
  __builtin_amdgcn_sched_barrier(0); }while(0)

union U32H2 { u32 u; _Float16 h[2]; };

__device__ __forceinline__ f16x8 cvt8(f32x4 a, f32x4 b){
  f16x8 r;
  r[0]=(_Float16)a[0]; r[1]=(_Float16)a[1]; r[2]=(_Float16)a[2]; r[3]=(_Float16)a[3];
  r[4]=(_Float16)b[0]; r[5]=(_Float16)b[1]; r[6]=(_Float16)b[2]; r[7]=(_Float16)b[3];
  return r;
}

// LSTM unit: a = {f,i,g,o} preacts; updates c, returns h. (R4-proven numerics.)
__device__ __forceinline__ float lstm_unit(const f32x4 a, float& cc){
  const float f = __builtin_amdgcn_rcpf(1.f + __expf(-a[0]));
  const float i = __builtin_amdgcn_rcpf(1.f + __expf(-a[1]));
  const float g = 1.f - 2.f*__builtin_amdgcn_rcpf(1.f + __expf(2.f*a[2]));
  const float o = __builtin_amdgcn_rcpf(1.f + __expf(-a[3]));
  cc = cc*f + i*g;
  const float tc = 1.f - 2.f*__builtin_amdgcn_rcpf(1.f + __expf(2.f*cc));
  return tc*o;
}

// 128 blocks = 16 groups x 8 waves; each block is ONE 64-lane wave owning 32
// hidden cols (8 m-tiles) for its group's 16 batch rows. No barriers, no LDS
// h-buffer. Protocol per step: spin on 8-tag sentinel vector (coalesced,
// uniform address) -> bulk-load 8 tag-free payload dwordx4 -> 64 MFMAs ->
// in-register pointwise -> 1 payload dwordx4 store -> vmcnt(0) -> sentinel.
// Safety: publish(s+1) happens only after sentinel-poll(s) which requires all
// waves' sentinels(s), each stored after that wave's payload-reads(s-1)
// completed => parity slot overwrite can never race a reader. Memset zeroes
// tags each launch; polled tags run 1..SEQ+1.
__global__ void __launch_bounds__(NTHR, 1)
lstm_seq(const float* __restrict__ x, const float* __restrict__ h0,
         const float* __restrict__ c0, const float* __restrict__ Wi,
         const float* __restrict__ bi, const float* __restrict__ Wh,
         const float* __restrict__ bh, const float* __restrict__ Wcls,
         const float* __restrict__ bcls,
         u32* __restrict__ pay, float* __restrict__ out)
{
  __shared__ u32 xlds[128*32];   // Wi slice, f16, XOR-swizzled (16 KB)

  const int bid = blockIdx.x;
  const int grp = bid & 15;
  const int wid = bid >> 4;          // 0..7: q = wid>>1, half = wid&1
  const int l   = threadIdx.x;
  const int l15 = l & 15, lhi = l >> 4;
  const int gate= l15 & 3, lr = l15 >> 2;
  const int colb= (wid>>1)*64 + (wid&1)*32;   // wave's 32-col base

  u32* sen = pay + 65536;            // payload: 2*16*2048 u32; sentinels after

  // ---- Wh register-resident: row-perm m -> (gate=m&3, jl=(m>>2)*8+mt) ----
  f16x8 wa[8][8];
#pragma unroll
  for (int mt=0; mt<8; ++mt){
    const float* wr = Wh + (size_t)(gate*NHID + colb + lr*8 + mt)*NHID + lhi*8;
#pragma unroll
    for (int kt=0; kt<8; ++kt)
      wa[mt][kt] = cvt8(*(const f32x4*)(wr + kt*32), *(const f32x4*)(wr + kt*32 + 4));
  }
  // ---- Wi -> swizzled LDS (read in the publish shadow each step) ----
  for (int idx = l; idx < 1024; idx += NTHR){
    const int rl = idx >> 3, seg = idx & 7;
    const int gt = rl >> 5, r2 = (rl >> 3) & 3, mt = rl & 7;
    const float* p = Wi + (size_t)(gt*NHID + colb + r2*8 + mt)*DIN + seg*8;
    const int w0 = (rl*32 + seg*4) ^ (((rl>>3)&7) << 2);
    *(f16x8*)&xlds[w0] = cvt8(*(const f32x4*)p, *(const f32x4*)(p+4));
  }
  // ---- bias (acc C-init) + cell state; lane owns cols colb+lhi*8+mt ----
  f32x4 binit[8]; float c[8];
#pragma unroll
  for (int mt=0; mt<8; ++mt){
    const int col = colb + lhi*8 + mt;
    f32x4 bv;
#pragma unroll
    for (int r=0;r<4;++r) bv[r] = bi[r*NHID+col] + bh[r*NHID+col];
    binit[mt] = bv;
    c[mt] = c0[(size_t)(grp*16+l15)*NHID + col];
  }

  // ---- publish state 0 (h0), sentinel tag 1, parity 0 ----
  {
    u32x4 pk;
#pragma unroll
    for (int j=0;j<4;++j){
      U32H2 u;
      u.h[0] = (_Float16)h0[(size_t)(grp*16+l15)*NHID + wid*32 + lhi*8 + 2*j];
      u.h[1] = (_Float16)h0[(size_t)(grp*16+l15)*NHID + wid*32 + lhi*8 + 2*j + 1];
      pk[j] = u.u;
    }
    u32* p0 = pay + grp*2048 + l15*128 + wid*16 + lhi*4;
    PSTORE(p0, pk);
    asm volatile("s_waitcnt vmcnt(0)" ::: "memory");
    if (l == 0){ const u32 one = 1u; SSTORE(sen + grp*32 + wid, one); }
  }

  // ---- x(0) -> acc init; prefetch x(1) ----
  const float* xrow = x + (size_t)(grp*16 + l15)*(SEQ*DIN) + lhi*8;
  f32x4 xp0 = *(const f32x4*)(xrow),    xp1 = *(const f32x4*)(xrow+4);
  f32x4 xp2 = *(const f32x4*)(xrow+32), xp3 = *(const f32x4*)(xrow+36);
  f32x4 acc[8];
  {
    const f16x8 xb0 = cvt8(xp0,xp1), xb1 = cvt8(xp2,xp3);
#pragma unroll
    for (int mt=0;mt<8;++mt){
      const int rl = gate*32 + lr*8 + mt;
      const int sw = ((rl>>3)&7) << 2;
      const f16x8 xa0 = *(const f16x8*)&xlds[(rl*32 + lhi*4) ^ sw];
      const f16x8 xa1 = *(const f16x8*)&xlds[(rl*32 + 16 + lhi*4) ^ sw];
      acc[mt] = MFMA16(xa1, xb1, MFMA16(xa0, xb0, binit[mt]));
    }
  }
  xp0 = *(const f32x4*)(xrow+DIN);    xp1 = *(const f32x4*)(xrow+DIN+4);
  xp2 = *(const f32x4*)(xrow+DIN+32); xp3 = *(const f32x4*)(xrow+DIN+36);

  const u32* ppoll = pay + grp*2048 + l15*128 + lhi*4;
  u32*       ppub  = pay + grp*2048 + l15*128 + wid*16 + lhi*4;
  const u32* spoll = sen + grp*32;
  u32*       spub  = sen + grp*32 + wid;

  for (int s=0; s<SEQ; ++s){
    const int pc = (s&1) ? 32768 : 0;        // consume parity
    const int pn = (s&1) ? 0 : 32768;        // produce parity
    const int sc = (s&1) ? 512 : 0;
    const int sn = (s&1) ? 0 : 512;
    const u32 stagc = (u32)(s+1), stagp = (u32)(s+2);

    // sentinel spin: 2 coalesced dwordx4 (8 tags), uniform address
    u32x4 s0q, s1q;
    const u32* sp = spoll + sc;
    for(;;){
      PLOAD(s0q, sp, 0); PLOAD(s1q, sp, 16);
      WAITBIND2(s0q, s1q);
      if (s0q[0]==stagc && s0q[1]==stagc && s0q[2]==stagc && s0q[3]==stagc &&
          s1q[0]==stagc && s1q[1]==stagc && s1q[2]==stagc && s1q[3]==stagc) break;
    }
    // payload bulk load: tag-free, stability guaranteed by sentinel
    const u32* pp = ppoll + pc;
    u32x4 v0,v1,v2,v3,v4,v5,v6,v7;
    PLOAD(v0,pp,0);   PLOAD(v1,pp,64);  PLOAD(v2,pp,128); PLOAD(v3,pp,192);
    PLOAD(v4,pp,256); PLOAD(v5,pp,320); PLOAD(v6,pp,384); PLOAD(v7,pp,448);
    WAITBIND8(v0,v1,v2,v3,v4,v5,v6,v7);

    // 64 recurrent MFMAs: 8 independent acc chains
#define HKT(K, VK) { const f16x8 hbk = __builtin_bit_cast(f16x8, VK); \
    _Pragma("unroll") for (int mt=0;mt<8;++mt) acc[mt] = MFMA16(wa[mt][K], hbk, acc[mt]); }
    HKT(0, v0) HKT(1, v1) HKT(2, v2) HKT(3, v3)
    HKT(4, v4) HKT(5, v5) HKT(6, v6) HKT(7, v7)
#undef HKT

    // pointwise in-register -> one dwordx4 payload (4 col-pairs)
    u32x4 pk;
#pragma unroll
    for (int jp=0; jp<4; ++jp){
      const float ha = lstm_unit(acc[2*jp],   c[2*jp]);
      const float hb2= lstm_unit(acc[2*jp+1], c[2*jp+1]);
      U32H2 u; u.h[0] = (_Float16)ha; u.h[1] = (_Float16)hb2;
      pk[jp] = u.u;
    }
    PSTORE(ppub + pn, pk);
    asm volatile("s_waitcnt vmcnt(0)" ::: "memory");
    if (l == 0) SSTORE(spub + sn, stagp);

    // publish shadow: next-step x-projection + x(s+2) prefetch
    {
      const f16x8 xb0 = cvt8(xp0,xp1), xb1 = cvt8(xp2,xp3);
      const int s2 = (s < SEQ-2) ? s+2 : SEQ-1;
      const float* px = xrow + (size_t)s2*DIN;
#pragma unroll
      for (int mt=0;mt<8;++mt){
        const int rl = gate*32 + lr*8 + mt;
        const int sw = ((rl>>3)&7) << 2;
        const f16x8 xa0 = *(const f16x8*)&xlds[(rl*32 + lhi*4) ^ sw];
        const f16x8 xa1 = *(const f16x8*)&xlds[(rl*32 + 16 + lhi*4) ^ sw];
        acc[mt] = MFMA16(xa1, xb1, MFMA16(xa0, xb0, binit[mt]));
      }
      xp0 = *(const f32x4*)(px);    xp1 = *(const f32x4*)(px+4);
      xp2 = *(const f32x4*)(px+32); xp3 = *(const f32x4*)(px+36);
    }
  }

  // ---- classifier: wave wid==0 of each group; final state SEQ at parity 0 ----
  if (wid == 0){
    const u32 ftag = (u32)(SEQ+1);
    u32x4 s0q, s1q;
    for(;;){
      PLOAD(s0q, spoll, 0); PLOAD(s1q, spoll, 16);
      WAITBIND2(s0q, s1q);
      if (s0q[0]==ftag && s0q[1]==ftag && s0q[2]==ftag && s0q[3]==ftag &&
          s1q[0]==ftag && s1q[1]==ftag && s1q[2]==ftag && s1q[3]==ftag) break;
    }
    u32x4 v0,v1,v2,v3,v4,v5,v6,v7;
    PLOAD(v0,ppoll,0);   PLOAD(v1,ppoll,64);  PLOAD(v2,ppoll,128); PLOAD(v3,ppoll,192);
    PLOAD(v4,ppoll,256); PLOAD(v5,ppoll,320); PLOAD(v6,ppoll,384); PLOAD(v7,ppoll,448);
    WAITBIND8(v0,v1,v2,v3,v4,v5,v6,v7);
    for (int j=0; j<10; ++j){
      float sum = 0.f;
#define CACC(K, VK) { const f16x8 hh = __builtin_bit_cast(f16x8, VK); \
      const float* wp = Wcls + j*NHID + K*32 + lhi*8; \
      const f32x4 wA = *(const f32x4*)wp, wB = *(const f32x4*)(wp+4); \
      sum += wA[0]*(float)hh[0] + wA[1]*(float)hh[1] + wA[2]*(float)hh[2] + wA[3]*(float)hh[3] \
           + wB[0]*(float)hh[4] + wB[1]*(float)hh[5] + wB[2]*(float)hh[6] + wB[3]*(float)hh[7]; }
      CACC(0, v0) CACC(1, v1) CACC(2, v2) CACC(3, v3)
      CACC(4, v4) CACC(5, v5) CACC(6, v6) CACC(7, v7)
#undef CACC
      sum += __shfl_xor(sum, 16);
      sum += __shfl_xor(sum, 32);
      if (l < 16) out[(grp*16 + l15)*10 + j] = sum + bcls[j];
    }
  }
}

extern "C" void kernel_launch(void* const* d_in, const int* in_sizes, int n_in,
                              void* d_out, int out_size, void* d_ws, size_t ws_size,
                              hipStream_t stream){
  const float* x    = (const float*)d_in[0];
  const float* h0   = (const float*)d_in[1];
  const float* c0   = (const float*)d_in[2];
  const float* Wi   = (const float*)d_in[3];
  const float* bi   = (const float*)d_in[4];
  const float* Wh   = (const float*)d_in[5];
  const float* bh   = (const float*)d_in[6];
  const float* Wcls = (const float*)d_in[7];
  const float* bcls = (const float*)d_in[8];

  u32* pay = (u32*)d_ws;
  // payload 2*16*2048 u32 = 262144 B; sentinels 2*16*32 u32 = 4096 B
  hipMemsetAsync(pay, 0, 262144 + 4096, stream);
  hipLaunchKernelGGL(lstm_seq, dim3(NBLK), dim3(NTHR), 0, stream,
                     x, h0, c0, Wi, bi, Wh, bh, Wcls, bcls,
                     pay, (float*)d_out);
}